// Round 4
// baseline (558.466 us; speedup 1.0000x reference)
//
#include <hip/hip_runtime.h>
#include <hip/hip_bf16.h>

// Problem constants (from reference)
constexpr int N_NODES = 100000;
constexpr int N_EDGES = 1000000;
constexpr int D_NODE  = 64;
constexpr int D_EDGE  = 32;
constexpr int D_GLOB  = 32;
constexpr int OUT_DIM = 64;
constexpr int K1 = 2*D_NODE + D_EDGE + D_GLOB; // 192
constexpr int K2 = D_NODE + OUT_DIM + D_GLOB;  // 160

typedef __bf16 bf16x8 __attribute__((ext_vector_type(8)));
typedef unsigned short ushort8_t __attribute__((ext_vector_type(8)));
typedef float floatx16 __attribute__((ext_vector_type(16)));

// LDS feature-tile row stride (bf16 elems): 400 B rows, 16B-aligned;
// 2-way bank aliasing only (free per m136).
constexpr int FS = 200;

constexpr int NB_SCAN = (N_NODES + 255) / 256;   // 391

// d_ws layout (bytes):
//   [0,      24576)   W1t bf16 [64][192]  (transposed: [n][k])
//   [24576,  45056)   W2t bf16 [64][160]
//   [45056,  46080)   ub  bf16 [16][32]
//   [46080,  447488)  cursor int[100352]   (deg -> exclusive offsets -> cursors)
//   [447488, 449536)  partials int[512]
//   [449536, 4449536) eperm int[1e6]       (dst-sorted edge ids)
//   [4449536, 17249536) xb bf16 [100000][64]
constexpr size_t WS_W1T  = 0;
constexpr size_t WS_W2T  = 24576;
constexpr size_t WS_UB   = 45056;
constexpr size_t WS_CUR  = 46080;
constexpr size_t WS_PART = 447488;
constexpr size_t WS_EPERM= 449536;
constexpr size_t WS_XB   = 4449536;

__device__ inline unsigned pack_bf2(float a, float b) {
    __hip_bfloat162 h = __float22bfloat162_rn(float2{a, b});
    return *(unsigned*)&h;
}

// ---------------------------------------------------------------------------
// Prep: bf16-convert x, u; bf16+transpose W1, W2; histogram deg[dst]
// (cursor region pre-zeroed by hipMemsetAsync).
// ---------------------------------------------------------------------------
__global__ __launch_bounds__(256) void prep_kernel(
    const float* __restrict__ x, const float* __restrict__ u,
    const float* __restrict__ W1, const float* __restrict__ W2,
    const int* __restrict__ ei,
    unsigned short* __restrict__ ws_w1t, unsigned short* __restrict__ ws_w2t,
    unsigned short* __restrict__ ws_ub, unsigned short* __restrict__ ws_xb,
    int* __restrict__ deg)
{
    const int t = blockIdx.x * 256 + threadIdx.x;
    const int stride = gridDim.x * 256;
    const float4* x4 = (const float4*)x;
    for (int i = t; i < N_NODES * 16; i += stride) {       // x -> bf16
        float4 v = x4[i];
        uint2 pk;
        pk.x = pack_bf2(v.x, v.y);
        pk.y = pack_bf2(v.z, v.w);
        *(uint2*)&ws_xb[i * 4] = pk;
    }
    for (int i = t; i < K1 * 64; i += stride) {            // W1 [k][n] -> [n][k]
        int k = i >> 6, n = i & 63;
        __hip_bfloat16 h = __float2bfloat16(W1[i]);
        ws_w1t[n * K1 + k] = *(unsigned short*)&h;
    }
    for (int i = t; i < K2 * 64; i += stride) {            // W2 [k][n] -> [n][k]
        int k = i >> 6, n = i & 63;
        __hip_bfloat16 h = __float2bfloat16(W2[i]);
        ws_w2t[n * K2 + k] = *(unsigned short*)&h;
    }
    for (int i = t; i < 16 * D_GLOB; i += stride) {        // u -> bf16
        __hip_bfloat16 h = __float2bfloat16(u[i]);
        ws_ub[i] = *(unsigned short*)&h;
    }
    for (int i = t; i < N_EDGES; i += stride)              // degree histogram
        atomicAdd(&deg[ei[N_EDGES + i]], 1);
}

// ---- CSR scan: exclusive prefix over deg (3 tiny kernels) ------------------
__global__ __launch_bounds__(256) void scan1_kernel(int* __restrict__ cursor,
                                                    int* __restrict__ partials)
{
    __shared__ int tmp[256];
    int i = blockIdx.x * 256 + threadIdx.x;
    int v = (i < N_NODES) ? cursor[i] : 0;
    tmp[threadIdx.x] = v;
    __syncthreads();
    for (int off = 1; off < 256; off <<= 1) {
        int t = (threadIdx.x >= off) ? tmp[threadIdx.x - off] : 0;
        __syncthreads();
        tmp[threadIdx.x] += t;
        __syncthreads();
    }
    if (i < N_NODES) cursor[i] = tmp[threadIdx.x] - v;     // exclusive
    if (threadIdx.x == 255) partials[blockIdx.x] = tmp[255];
}

__global__ __launch_bounds__(512) void scan2_kernel(int* __restrict__ partials)
{
    __shared__ int tmp[512];
    int v = (threadIdx.x < NB_SCAN) ? partials[threadIdx.x] : 0;
    tmp[threadIdx.x] = v;
    __syncthreads();
    for (int off = 1; off < 512; off <<= 1) {
        int t = (threadIdx.x >= off) ? tmp[threadIdx.x - off] : 0;
        __syncthreads();
        tmp[threadIdx.x] += t;
        __syncthreads();
    }
    if (threadIdx.x < NB_SCAN) partials[threadIdx.x] = tmp[threadIdx.x] - v;
}

__global__ __launch_bounds__(256) void scan3_kernel(int* __restrict__ cursor,
                                                    const int* __restrict__ partials)
{
    int i = blockIdx.x * 256 + threadIdx.x;
    if (i < N_NODES) cursor[i] += partials[blockIdx.x];
}

// ---- scatter edge ids into dst-sorted order --------------------------------
__global__ __launch_bounds__(256) void scatter_kernel(
    const int* __restrict__ ei, int* __restrict__ cursor,
    int* __restrict__ eperm)
{
    int t = blockIdx.x * 256 + threadIdx.x;
    if (t < N_EDGES) {
        int d = ei[N_EDGES + t];
        int pos = atomicAdd(&cursor[d], 1);
        eperm[pos] = t;
    }
}

// ---------------------------------------------------------------------------
// Edge kernel: processes 64 dst-sorted edges per block.
// msg = relu([x[dst],x[src],ea,u[b[dst]]]@W1 + b1) via 32x32x16 MFMA,
// staged to LDS fp32, then segmented run-reduction over same-dst rows:
// one wave-coalesced atomicAdd per (run, 64 channels).
// ---------------------------------------------------------------------------
__global__ __launch_bounds__(256, 4) void edge_kernel(
    const unsigned short* __restrict__ xb, const int* __restrict__ ei,
    const float* __restrict__ ea, const unsigned short* __restrict__ ub,
    const int* __restrict__ batch, const unsigned short* __restrict__ W1t,
    const float* __restrict__ b1, const int* __restrict__ eperm,
    float* __restrict__ agg)
{
    __shared__ __align__(16) char smem_raw[64 * FS * 2];  // 25600 B (aliased)
    __shared__ int s_eid[64];
    __shared__ int s_dst[64];
    __shared__ int s_src[64];
    __shared__ int s_b[64];
    unsigned short* feats = (unsigned short*)smem_raw;    // [64][FS] bf16
    float*          msg   = (float*)smem_raw;             // [64][64] fp32 (after MFMA)

    const int tid  = threadIdx.x;
    const int lane = tid & 63;
    const int wv   = tid >> 6;
    const int tile = blockIdx.x;
    const int eh   = wv >> 1;
    const int nh   = wv & 1;
    const int col  = lane & 31;
    const int half = lane >> 5;

    if (tid < 64) {
        int eid = eperm[tile * 64 + tid];
        s_eid[tid] = eid;
        int d = ei[N_EDGES + eid];          // dst
        s_dst[tid] = d;
        s_src[tid] = ei[eid];               // src
        s_b[tid]   = batch[d];
    }

    // B fragments: n = nh*32+col, k = s*16 + half*8 + j (L2-hot W1t)
    bf16x8 Bf[12];
    #pragma unroll
    for (int s = 0; s < 12; ++s)
        Bf[s] = __builtin_bit_cast(bf16x8,
            *(const ushort8_t*)&W1t[(nh*32 + col) * K1 + s*16 + half*8]);
    const float b1v = b1[nh*32 + col];

    __syncthreads();

    // Gather: 64 edges x 24 16B-chunks (x[dst]:8 | x[src]:8 | ea:4 | u:4)
    const float4* ea4 = (const float4*)ea;
    for (int q = tid; q < 64 * 24; q += 256) {
        int el = q / 24;
        int c  = q - el * 24;
        uint4 pk;
        if (c < 8)       pk = *(const uint4*)&xb[s_dst[el] * 64 + c * 8];
        else if (c < 16) pk = *(const uint4*)&xb[s_src[el] * 64 + (c - 8) * 8];
        else if (c < 20) {
            float4 v0 = ea4[(size_t)s_eid[el] * 8 + (c - 16) * 2 + 0];
            float4 v1 = ea4[(size_t)s_eid[el] * 8 + (c - 16) * 2 + 1];
            pk.x = pack_bf2(v0.x, v0.y); pk.y = pack_bf2(v0.z, v0.w);
            pk.z = pack_bf2(v1.x, v1.y); pk.w = pack_bf2(v1.z, v1.w);
        } else           pk = *(const uint4*)&ub[s_b[el] * 32 + (c - 20) * 8];
        *(uint4*)&feats[el * FS + c * 8] = pk;
    }
    __syncthreads();

    // MFMA: A rows = eh*32 + col, k = s*16 + half*8 + j
    floatx16 acc = {0,0,0,0,0,0,0,0,0,0,0,0,0,0,0,0};
    #pragma unroll
    for (int s = 0; s < 12; ++s) {
        bf16x8 a = __builtin_bit_cast(bf16x8,
            *(const ushort8_t*)&feats[(eh*32 + col) * FS + s*16 + half*8]);
        acc = __builtin_amdgcn_mfma_f32_32x32x16_bf16(a, Bf[s], acc, 0, 0, 0);
    }
    __syncthreads();   // all waves done reading feats; smem becomes msg

    // Stage bias+relu'd messages: C layout col=lane&31, row=(r&3)+8*(r>>2)+4*half
    #pragma unroll
    for (int r = 0; r < 16; ++r) {
        int e = eh*32 + (r & 3) + 8*(r >> 2) + 4*half;
        float vv = acc[r] + b1v;
        msg[e * 64 + nh*32 + col] = vv > 0.f ? vv : 0.f;
    }
    __syncthreads();

    // Segmented reduction: wave wv owns edges [16wv,16wv+16), lane = channel.
    // s_dst is identical across lanes -> wave-uniform branches, coalesced atomics.
    {
        const int base_e = wv * 16;
        int cur = s_dst[base_e];
        float run = 0.f;
        #pragma unroll
        for (int i = 0; i < 16; ++i) {
            int e = base_e + i;
            int d = s_dst[e];
            if (d != cur) {
                atomicAdd(&agg[(size_t)cur * 64 + lane], run);
                run = 0.f;
                cur = d;
            }
            run += msg[e * 64 + lane];
        }
        atomicAdd(&agg[(size_t)cur * 64 + lane], run);
    }
}

// ---------------------------------------------------------------------------
// Node kernel (32x32x16 MFMA): out = relu([x, agg, u[batch]] @ W2 + b2)
// agg read fp32 from d_out; in-place, row-exclusive per block.
// ---------------------------------------------------------------------------
__global__ __launch_bounds__(256, 4) void node_kernel(
    const unsigned short* __restrict__ xb, const unsigned short* __restrict__ ub,
    const int* __restrict__ batch, const unsigned short* __restrict__ W2t,
    const float* __restrict__ b2, float* __restrict__ out)
{
    __shared__ __align__(16) unsigned short smem[64 * FS];
    __shared__ int s_b[64];

    const int tid  = threadIdx.x;
    const int lane = tid & 63;
    const int wv   = tid >> 6;
    const int base = blockIdx.x * 64;
    const int eh   = wv >> 1;
    const int nh   = wv & 1;
    const int col  = lane & 31;
    const int half = lane >> 5;

    if (tid < 64) {
        int n = base + tid;
        s_b[tid] = (n < N_NODES) ? batch[n] : 0;
    }

    bf16x8 Bf[10];
    #pragma unroll
    for (int s = 0; s < 10; ++s)
        Bf[s] = __builtin_bit_cast(bf16x8,
            *(const ushort8_t*)&W2t[(nh*32 + col) * K2 + s*16 + half*8]);
    const float b2v = b2[nh*32 + col];

    __syncthreads();

    const float4* o4 = (const float4*)out;
    for (int q = tid; q < 64 * 20; q += 256) {
        int nl = q / 20;
        int c  = q - nl * 20;
        int n  = base + nl;
        uint4 pk;
        if (n >= N_NODES) pk = uint4{0, 0, 0, 0};
        else if (c < 8)   pk = *(const uint4*)&xb[n * 64 + c * 8];
        else if (c < 16) {
            float4 v0 = o4[n * 16 + (c - 8) * 2 + 0];
            float4 v1 = o4[n * 16 + (c - 8) * 2 + 1];
            pk.x = pack_bf2(v0.x, v0.y); pk.y = pack_bf2(v0.z, v0.w);
            pk.z = pack_bf2(v1.x, v1.y); pk.w = pack_bf2(v1.z, v1.w);
        } else            pk = *(const uint4*)&ub[s_b[nl] * 32 + (c - 16) * 8];
        *(uint4*)&smem[nl * FS + c * 8] = pk;
    }
    __syncthreads();

    floatx16 acc = {0,0,0,0,0,0,0,0,0,0,0,0,0,0,0,0};
    #pragma unroll
    for (int s = 0; s < 10; ++s) {
        bf16x8 a = __builtin_bit_cast(bf16x8,
            *(const ushort8_t*)&smem[(eh*32 + col) * FS + s*16 + half*8]);
        acc = __builtin_amdgcn_mfma_f32_32x32x16_bf16(a, Bf[s], acc, 0, 0, 0);
    }

    #pragma unroll
    for (int r = 0; r < 16; ++r) {
        int n = base + eh*32 + (r & 3) + 8*(r >> 2) + 4*half;
        if (n < N_NODES) {
            float vv = acc[r] + b2v;
            out[n * 64 + nh*32 + col] = vv > 0.f ? vv : 0.f;
        }
    }
}

extern "C" void kernel_launch(void* const* d_in, const int* in_sizes, int n_in,
                              void* d_out, int out_size, void* d_ws, size_t ws_size,
                              hipStream_t stream) {
    const float* x     = (const float*)d_in[0];
    const int*   ei    = (const int*)d_in[1];
    const float* ea    = (const float*)d_in[2];
    const float* u     = (const float*)d_in[3];
    const int*   batch = (const int*)d_in[4];
    const float* W1    = (const float*)d_in[5];
    const float* b1    = (const float*)d_in[6];
    const float* W2    = (const float*)d_in[7];
    const float* b2    = (const float*)d_in[8];
    float* out = (float*)d_out;

    unsigned short* ws_w1t = (unsigned short*)((char*)d_ws + WS_W1T);
    unsigned short* ws_w2t = (unsigned short*)((char*)d_ws + WS_W2T);
    unsigned short* ws_ub  = (unsigned short*)((char*)d_ws + WS_UB);
    int*            cursor = (int*)((char*)d_ws + WS_CUR);
    int*            parts  = (int*)((char*)d_ws + WS_PART);
    int*            eperm  = (int*)((char*)d_ws + WS_EPERM);
    unsigned short* ws_xb  = (unsigned short*)((char*)d_ws + WS_XB);

    // agg accumulates in d_out; zero it + the histogram region (capture-safe)
    hipMemsetAsync(out, 0, (size_t)out_size * sizeof(float), stream);
    hipMemsetAsync(cursor, 0, (WS_EPERM - WS_CUR), stream);

    prep_kernel<<<2048, 256, 0, stream>>>(x, u, W1, W2, ei,
                                          ws_w1t, ws_w2t, ws_ub, ws_xb, cursor);
    scan1_kernel<<<NB_SCAN, 256, 0, stream>>>(cursor, parts);
    scan2_kernel<<<1, 512, 0, stream>>>(parts);
    scan3_kernel<<<NB_SCAN, 256, 0, stream>>>(cursor, parts);
    scatter_kernel<<<(N_EDGES + 255) / 256, 256, 0, stream>>>(ei, cursor, eperm);
    edge_kernel<<<N_EDGES / 64, 256, 0, stream>>>(ws_xb, ei, ea, ws_ub, batch,
                                                  ws_w1t, b1, eperm, out);
    node_kernel<<<(N_NODES + 63) / 64, 256, 0, stream>>>(ws_xb, ws_ub, batch,
                                                         ws_w2t, b2, out);
}

// Round 5
// 503.888 us; speedup vs baseline: 1.1083x; 1.1083x over previous
//
#include <hip/hip_runtime.h>
#include <hip/hip_bf16.h>

// Problem constants (from reference)
constexpr int N_NODES = 100000;
constexpr int N_EDGES = 1000000;
constexpr int D_GLOB  = 32;
constexpr int K1 = 192;   // [x_dst(64) | x_src(64) | ea(32) | u(32)]
constexpr int K2 = 160;   // [x(64) | agg(64) | u(32)]

typedef __bf16 bf16x8 __attribute__((ext_vector_type(8)));
typedef unsigned short ushort8_t __attribute__((ext_vector_type(8)));
typedef float floatx16 __attribute__((ext_vector_type(16)));

constexpr int NB_SCAN = (N_NODES + 255) / 256;   // 391
constexpr int FS = 200;                          // node-kernel LDS row stride

// d_ws layout (bytes):
constexpr size_t WS_W1T  = 0;         // bf16 [64][192]  W1 transposed [n][k]
constexpr size_t WS_W2T  = 24576;     // bf16 [64][160]
constexpr size_t WS_UB   = 45056;     // bf16 [16][32]
constexpr size_t WS_CUR  = 46080;     // int [100352]  deg -> in-block-excl scan -> cursors
constexpr size_t WS_PART = 447488;    // int [512]     block partial sums (exclusive)
constexpr size_t WS_QUAD = 449536;    // uint64 [1M]   dst-sorted {src,dst,eid,bat}
constexpr size_t WS_XB   = 8449536;   // bf16 [100000][64]
constexpr size_t WS_EAB  = 21249536;  // bf16 [1M][32]  (optional, if ws_size allows)
constexpr size_t WS_EAB_END = 85249536;

__device__ inline unsigned pack_bf2(float a, float b) {
    __hip_bfloat162 h = __float22bfloat162_rn(float2{a, b});
    return *(unsigned*)&h;
}

// ---------------------------------------------------------------------------
// Prep: bf16-convert x (and optionally ea); bf16+transpose W1, W2; u -> bf16;
// degree histogram over dst. (cursor region pre-zeroed by hipMemsetAsync.)
// ---------------------------------------------------------------------------
__global__ __launch_bounds__(256) void prep_kernel(
    const float* __restrict__ x, const float* __restrict__ ea,
    const float* __restrict__ u,
    const float* __restrict__ W1, const float* __restrict__ W2,
    const int* __restrict__ ei, int do_ea,
    unsigned short* __restrict__ w1t, unsigned short* __restrict__ w2t,
    unsigned short* __restrict__ ub, unsigned short* __restrict__ xb,
    unsigned short* __restrict__ eab, int* __restrict__ deg)
{
    const int t = blockIdx.x * 256 + threadIdx.x;
    const int stride = gridDim.x * 256;
    const float4* x4 = (const float4*)x;
    for (int i = t; i < N_NODES * 16; i += stride) {       // x -> bf16
        float4 v = x4[i];
        uint2 pk;
        pk.x = pack_bf2(v.x, v.y);
        pk.y = pack_bf2(v.z, v.w);
        *(uint2*)&xb[i * 4] = pk;
    }
    if (do_ea) {
        const float4* ea4 = (const float4*)ea;
        for (int i = t; i < N_EDGES * 8; i += stride) {    // ea -> bf16
            float4 v = ea4[i];
            uint2 pk;
            pk.x = pack_bf2(v.x, v.y);
            pk.y = pack_bf2(v.z, v.w);
            *(uint2*)&eab[i * 4] = pk;
        }
    }
    for (int i = t; i < K1 * 64; i += stride) {            // W1 [k][n] -> [n][k]
        int k = i >> 6, n = i & 63;
        __hip_bfloat16 h = __float2bfloat16(W1[i]);
        w1t[n * K1 + k] = *(unsigned short*)&h;
    }
    for (int i = t; i < K2 * 64; i += stride) {            // W2 [k][n] -> [n][k]
        int k = i >> 6, n = i & 63;
        __hip_bfloat16 h = __float2bfloat16(W2[i]);
        w2t[n * K2 + k] = *(unsigned short*)&h;
    }
    for (int i = t; i < 16 * D_GLOB; i += stride) {        // u -> bf16
        __hip_bfloat16 h = __float2bfloat16(u[i]);
        ub[i] = *(unsigned short*)&h;
    }
    for (int i = t; i < N_EDGES; i += stride)              // degree histogram
        atomicAdd(&deg[ei[N_EDGES + i]], 1);
}

// ---- CSR scan: in-block exclusive over deg + exclusive block partials ------
__global__ __launch_bounds__(256) void scan1_kernel(int* __restrict__ cursor,
                                                    int* __restrict__ partials)
{
    __shared__ int tmp[256];
    int i = blockIdx.x * 256 + threadIdx.x;
    int v = (i < N_NODES) ? cursor[i] : 0;
    tmp[threadIdx.x] = v;
    __syncthreads();
    for (int off = 1; off < 256; off <<= 1) {
        int t = (threadIdx.x >= off) ? tmp[threadIdx.x - off] : 0;
        __syncthreads();
        tmp[threadIdx.x] += t;
        __syncthreads();
    }
    if (i < N_NODES) cursor[i] = tmp[threadIdx.x] - v;     // in-block exclusive
    if (threadIdx.x == 255) partials[blockIdx.x] = tmp[255];
}

__global__ __launch_bounds__(512) void scan2_kernel(int* __restrict__ partials)
{
    __shared__ int tmp[512];
    int v = (threadIdx.x < NB_SCAN) ? partials[threadIdx.x] : 0;
    tmp[threadIdx.x] = v;
    __syncthreads();
    for (int off = 1; off < 512; off <<= 1) {
        int t = (threadIdx.x >= off) ? tmp[threadIdx.x - off] : 0;
        __syncthreads();
        tmp[threadIdx.x] += t;
        __syncthreads();
    }
    if (threadIdx.x < NB_SCAN) partials[threadIdx.x] = tmp[threadIdx.x] - v;
}

// ---- scatter: dst-sorted packed index stream {src,dst,eid,bat} -------------
__global__ __launch_bounds__(256) void scatter_kernel(
    const int* __restrict__ ei, const int* __restrict__ batch,
    int* __restrict__ cursor, const int* __restrict__ partials,
    unsigned long long* __restrict__ quad)
{
    int t = blockIdx.x * 256 + threadIdx.x;
    if (t < N_EDGES) {
        int d = ei[N_EDGES + t];
        int s = ei[t];
        int b = batch[d];
        int pos = atomicAdd(&cursor[d], 1) + partials[d >> 8];
        quad[pos] = (unsigned long long)(unsigned)s
                  | ((unsigned long long)(unsigned)d << 17)
                  | ((unsigned long long)(unsigned)t << 34)
                  | ((unsigned long long)(unsigned)b << 54);
    }
}

// ---------------------------------------------------------------------------
// Edge kernel: one 64-edge dst-sorted tile per block, barrier-free main body.
// Lane owns row=eh*32+col of the A operand and loads its 12 A-frags (16 B)
// straight from global (xb[dst], xb[src], ea, ub[bat]) — max MLP, no LDS
// staging. msg staged to LDS only for the segmented dst-run reduction.
// ---------------------------------------------------------------------------
template<bool EAB>
__global__ __launch_bounds__(256, 8) void edge_kernel(
    const unsigned short* __restrict__ xb, const float* __restrict__ ea,
    const unsigned short* __restrict__ eab, const unsigned short* __restrict__ ub,
    const unsigned short* __restrict__ W1t, const float* __restrict__ b1,
    const unsigned long long* __restrict__ quad, float* __restrict__ agg)
{
    __shared__ __align__(16) float msg[64 * 64];   // 16 KB
    __shared__ int s_dst[64];

    const int tid  = threadIdx.x;
    const int lane = tid & 63;
    const int wv   = tid >> 6;
    const int tile = blockIdx.x;
    const int eh   = wv >> 1;            // edge half: rows [eh*32, eh*32+32)
    const int nh   = wv & 1;             // channel half
    const int col  = lane & 31;
    const int half = lane >> 5;

    // Per-lane indices for A-row (eh*32 + col); both halves load same addr.
    unsigned long long p = quad[tile * 64 + eh * 32 + col];
    const int e_src = (int)(p & 0x1FFFF);
    const int e_dst = (int)((p >> 17) & 0x1FFFF);
    const int e_eid = (int)((p >> 34) & 0xFFFFF);
    const int e_b   = (int)(p >> 54);
    if (nh == 0 && half == 0) s_dst[eh * 32 + col] = e_dst;

    const int ch = nh * 32 + col;        // this lane's output channel
    const float b1v = b1[ch];

    floatx16 acc = {0,0,0,0,0,0,0,0,0,0,0,0,0,0,0,0};
    #pragma unroll
    for (int s = 0; s < 12; ++s) {
        bf16x8 a;
        if (s < 4) {
            a = __builtin_bit_cast(bf16x8,
                *(const ushort8_t*)&xb[e_dst * 64 + s * 16 + half * 8]);
        } else if (s < 8) {
            a = __builtin_bit_cast(bf16x8,
                *(const ushort8_t*)&xb[e_src * 64 + (s - 4) * 16 + half * 8]);
        } else if (s < 10) {
            if (EAB) {
                a = __builtin_bit_cast(bf16x8,
                    *(const ushort8_t*)&eab[e_eid * 32 + (s - 8) * 16 + half * 8]);
            } else {
                const float4* ea4 = (const float4*)ea;
                float4 v0 = ea4[e_eid * 8 + (s - 8) * 4 + half * 2 + 0];
                float4 v1 = ea4[e_eid * 8 + (s - 8) * 4 + half * 2 + 1];
                uint4 uu;
                uu.x = pack_bf2(v0.x, v0.y); uu.y = pack_bf2(v0.z, v0.w);
                uu.z = pack_bf2(v1.x, v1.y); uu.w = pack_bf2(v1.z, v1.w);
                a = __builtin_bit_cast(bf16x8, uu);
            }
        } else {
            a = __builtin_bit_cast(bf16x8,
                *(const ushort8_t*)&ub[e_b * 32 + (s - 10) * 16 + half * 8]);
        }
        bf16x8 b = __builtin_bit_cast(bf16x8,
            *(const ushort8_t*)&W1t[ch * K1 + s * 16 + half * 8]);
        acc = __builtin_amdgcn_mfma_f32_32x32x16_bf16(a, b, acc, 0, 0, 0);
    }

    // Stage bias+relu'd msg: C layout col(=ch) fixed, row=(r&3)+8*(r>>2)+4*half
    #pragma unroll
    for (int r = 0; r < 16; ++r) {
        int row = eh * 32 + (r & 3) + 8 * (r >> 2) + 4 * half;
        float vv = acc[r] + b1v;
        msg[row * 64 + ch] = vv > 0.f ? vv : 0.f;
    }
    __syncthreads();

    // Segmented dst-run reduction: wave wv owns edges [16wv,16wv+16), lane=ch.
    {
        const int base_e = wv * 16;
        int cur = s_dst[base_e];
        float run = 0.f;
        #pragma unroll
        for (int i = 0; i < 16; ++i) {
            int e = base_e + i;
            int d = s_dst[e];
            if (d != cur) {
                atomicAdd(&agg[(size_t)cur * 64 + lane], run);
                run = 0.f;
                cur = d;
            }
            run += msg[e * 64 + lane];
        }
        atomicAdd(&agg[(size_t)cur * 64 + lane], run);
    }
}

// ---------------------------------------------------------------------------
// Node kernel (32x32x16 MFMA): out = relu([x, agg, u[batch]] @ W2 + b2)
// agg read fp32 from d_out; in-place, row-exclusive per block.
// ---------------------------------------------------------------------------
__global__ __launch_bounds__(256, 4) void node_kernel(
    const unsigned short* __restrict__ xb, const unsigned short* __restrict__ ub,
    const int* __restrict__ batch, const unsigned short* __restrict__ W2t,
    const float* __restrict__ b2, float* __restrict__ out)
{
    __shared__ __align__(16) unsigned short smem[64 * FS];
    __shared__ int s_b[64];

    const int tid  = threadIdx.x;
    const int lane = tid & 63;
    const int wv   = tid >> 6;
    const int base = blockIdx.x * 64;
    const int eh   = wv >> 1;
    const int nh   = wv & 1;
    const int col  = lane & 31;
    const int half = lane >> 5;

    if (tid < 64) {
        int n = base + tid;
        s_b[tid] = (n < N_NODES) ? batch[n] : 0;
    }

    bf16x8 Bf[10];
    #pragma unroll
    for (int s = 0; s < 10; ++s)
        Bf[s] = __builtin_bit_cast(bf16x8,
            *(const ushort8_t*)&W2t[(nh*32 + col) * K2 + s*16 + half*8]);
    const float b2v = b2[nh*32 + col];

    __syncthreads();

    const float4* o4 = (const float4*)out;
    for (int q = tid; q < 64 * 20; q += 256) {
        int nl = q / 20;
        int c  = q - nl * 20;
        int n  = base + nl;
        uint4 pk;
        if (n >= N_NODES) pk = uint4{0, 0, 0, 0};
        else if (c < 8)   pk = *(const uint4*)&xb[n * 64 + c * 8];
        else if (c < 16) {
            float4 v0 = o4[n * 16 + (c - 8) * 2 + 0];
            float4 v1 = o4[n * 16 + (c - 8) * 2 + 1];
            pk.x = pack_bf2(v0.x, v0.y); pk.y = pack_bf2(v0.z, v0.w);
            pk.z = pack_bf2(v1.x, v1.y); pk.w = pack_bf2(v1.z, v1.w);
        } else            pk = *(const uint4*)&ub[s_b[nl] * 32 + (c - 16) * 8];
        *(uint4*)&smem[nl * FS + c * 8] = pk;
    }
    __syncthreads();

    floatx16 acc = {0,0,0,0,0,0,0,0,0,0,0,0,0,0,0,0};
    #pragma unroll
    for (int s = 0; s < 10; ++s) {
        bf16x8 a = __builtin_bit_cast(bf16x8,
            *(const ushort8_t*)&smem[(eh*32 + col) * FS + s*16 + half*8]);
        acc = __builtin_amdgcn_mfma_f32_32x32x16_bf16(a, Bf[s], acc, 0, 0, 0);
    }

    #pragma unroll
    for (int r = 0; r < 16; ++r) {
        int n = base + eh*32 + (r & 3) + 8*(r >> 2) + 4*half;
        if (n < N_NODES) {
            float vv = acc[r] + b2v;
            out[n * 64 + nh*32 + col] = vv > 0.f ? vv : 0.f;
        }
    }
}

extern "C" void kernel_launch(void* const* d_in, const int* in_sizes, int n_in,
                              void* d_out, int out_size, void* d_ws, size_t ws_size,
                              hipStream_t stream) {
    const float* x     = (const float*)d_in[0];
    const int*   ei    = (const int*)d_in[1];
    const float* ea    = (const float*)d_in[2];
    const float* u     = (const float*)d_in[3];
    const int*   batch = (const int*)d_in[4];
    const float* W1    = (const float*)d_in[5];
    const float* b1    = (const float*)d_in[6];
    const float* W2    = (const float*)d_in[7];
    const float* b2    = (const float*)d_in[8];
    float* out = (float*)d_out;

    unsigned short* w1t  = (unsigned short*)((char*)d_ws + WS_W1T);
    unsigned short* w2t  = (unsigned short*)((char*)d_ws + WS_W2T);
    unsigned short* ub   = (unsigned short*)((char*)d_ws + WS_UB);
    int*            cur  = (int*)((char*)d_ws + WS_CUR);
    int*            part = (int*)((char*)d_ws + WS_PART);
    unsigned long long* quad = (unsigned long long*)((char*)d_ws + WS_QUAD);
    unsigned short* xb   = (unsigned short*)((char*)d_ws + WS_XB);
    unsigned short* eab  = (unsigned short*)((char*)d_ws + WS_EAB);

    const bool big = ws_size >= WS_EAB_END;   // room for bf16 edge_attr copy?

    // agg accumulates in d_out; zero it + histogram/partials region
    hipMemsetAsync(out, 0, (size_t)out_size * sizeof(float), stream);
    hipMemsetAsync(cur, 0, WS_QUAD - WS_CUR, stream);

    prep_kernel<<<2048, 256, 0, stream>>>(x, ea, u, W1, W2, ei, big ? 1 : 0,
                                          w1t, w2t, ub, xb, eab, cur);
    scan1_kernel<<<NB_SCAN, 256, 0, stream>>>(cur, part);
    scan2_kernel<<<1, 512, 0, stream>>>(part);
    scatter_kernel<<<(N_EDGES + 255) / 256, 256, 0, stream>>>(ei, batch, cur, part, quad);
    if (big)
        edge_kernel<true><<<N_EDGES / 64, 256, 0, stream>>>(xb, ea, eab, ub, w1t, b1, quad, out);
    else
        edge_kernel<false><<<N_EDGES / 64, 256, 0, stream>>>(xb, ea, eab, ub, w1t, b1, quad, out);
    node_kernel<<<(N_NODES + 63) / 64, 256, 0, stream>>>(xb, ub, batch, w2t, b2, out);
}

// Round 6
// 499.788 us; speedup vs baseline: 1.1174x; 1.0082x over previous
//
#include <hip/hip_runtime.h>
#include <hip/hip_bf16.h>

// Problem constants (from reference)
constexpr int N_NODES = 100000;
constexpr int N_EDGES = 1000000;
constexpr int D_GLOB  = 32;
constexpr int K1 = 192;   // [x_dst(64) | x_src(64) | ea(32) | u(32)]
constexpr int K2 = 160;   // [x(64) | agg(64) | u(32)]

typedef __bf16 bf16x8 __attribute__((ext_vector_type(8)));
typedef unsigned short ushort8_t __attribute__((ext_vector_type(8)));
typedef float floatx16 __attribute__((ext_vector_type(16)));

constexpr int NB_SCAN = (N_NODES + 255) / 256;   // 391

// d_ws layout (bytes):
constexpr size_t WS_W1T  = 0;         // bf16 [64][192]  W1 transposed [n][k]
constexpr size_t WS_W2T  = 24576;     // bf16 [64][160]
constexpr size_t WS_UB   = 45056;     // bf16 [16][32]
constexpr size_t WS_CUR  = 46080;     // int [100352]  deg -> in-block-excl scan -> cursors
constexpr size_t WS_PART = 447488;    // int [512]     exclusive block partials
constexpr size_t WS_QUAD = 449536;    // uint64 [1M]   dst-sorted {src,dst,eid,bat}
constexpr size_t WS_XB   = 8449536;   // bf16 [100000][64]
constexpr size_t WS_EAB  = 21249536;  // bf16 [1M][32] in dst-SORTED order (optional)
constexpr size_t WS_EAB_END = 85249536;

__device__ inline unsigned pack_bf2(float a, float b) {
    __hip_bfloat162 h = __float22bfloat162_rn(float2{a, b});
    return *(unsigned*)&h;
}

// ---------------------------------------------------------------------------
// Prep: bf16-convert x, u; bf16+transpose W1, W2; degree histogram over dst.
// (cursor region pre-zeroed by hipMemsetAsync.)
// ---------------------------------------------------------------------------
__global__ __launch_bounds__(256) void prep_kernel(
    const float* __restrict__ x, const float* __restrict__ u,
    const float* __restrict__ W1, const float* __restrict__ W2,
    const int* __restrict__ ei,
    unsigned short* __restrict__ w1t, unsigned short* __restrict__ w2t,
    unsigned short* __restrict__ ub, unsigned short* __restrict__ xb,
    int* __restrict__ deg)
{
    const int t = blockIdx.x * 256 + threadIdx.x;
    const int stride = gridDim.x * 256;
    const float4* x4 = (const float4*)x;
    for (int i = t; i < N_NODES * 16; i += stride) {       // x -> bf16
        float4 v = x4[i];
        uint2 pk;
        pk.x = pack_bf2(v.x, v.y);
        pk.y = pack_bf2(v.z, v.w);
        *(uint2*)&xb[i * 4] = pk;
    }
    for (int i = t; i < K1 * 64; i += stride) {            // W1 [k][n] -> [n][k]
        int k = i >> 6, n = i & 63;
        __hip_bfloat16 h = __float2bfloat16(W1[i]);
        w1t[n * K1 + k] = *(unsigned short*)&h;
    }
    for (int i = t; i < K2 * 64; i += stride) {            // W2 [k][n] -> [n][k]
        int k = i >> 6, n = i & 63;
        __hip_bfloat16 h = __float2bfloat16(W2[i]);
        w2t[n * K2 + k] = *(unsigned short*)&h;
    }
    for (int i = t; i < 16 * D_GLOB; i += stride) {        // u -> bf16
        __hip_bfloat16 h = __float2bfloat16(u[i]);
        ub[i] = *(unsigned short*)&h;
    }
    for (int i = t; i < N_EDGES; i += stride)              // degree histogram
        atomicAdd(&deg[ei[N_EDGES + i]], 1);
}

// ---- CSR scan: in-block exclusive over deg + exclusive block partials ------
__global__ __launch_bounds__(256) void scan1_kernel(int* __restrict__ cursor,
                                                    int* __restrict__ partials)
{
    __shared__ int tmp[256];
    int i = blockIdx.x * 256 + threadIdx.x;
    int v = (i < N_NODES) ? cursor[i] : 0;
    tmp[threadIdx.x] = v;
    __syncthreads();
    for (int off = 1; off < 256; off <<= 1) {
        int t = (threadIdx.x >= off) ? tmp[threadIdx.x - off] : 0;
        __syncthreads();
        tmp[threadIdx.x] += t;
        __syncthreads();
    }
    if (i < N_NODES) cursor[i] = tmp[threadIdx.x] - v;     // in-block exclusive
    if (threadIdx.x == 255) partials[blockIdx.x] = tmp[255];
}

__global__ __launch_bounds__(512) void scan2_kernel(int* __restrict__ partials)
{
    __shared__ int tmp[512];
    int v = (threadIdx.x < NB_SCAN) ? partials[threadIdx.x] : 0;
    tmp[threadIdx.x] = v;
    __syncthreads();
    for (int off = 1; off < 512; off <<= 1) {
        int t = (threadIdx.x >= off) ? tmp[threadIdx.x - off] : 0;
        __syncthreads();
        tmp[threadIdx.x] += t;
        __syncthreads();
    }
    if (threadIdx.x < NB_SCAN) partials[threadIdx.x] = tmp[threadIdx.x] - v;
}

// ---- scatter: packed index stream {src,dst,eid,bat} + ea rows, dst-sorted --
__global__ __launch_bounds__(256) void scatter_kernel(
    const int* __restrict__ ei, const int* __restrict__ batch,
    const float* __restrict__ ea, int* __restrict__ cursor,
    const int* __restrict__ partials, unsigned long long* __restrict__ quad,
    unsigned short* __restrict__ eab, int do_ea)
{
    int t = blockIdx.x * 256 + threadIdx.x;
    if (t < N_EDGES) {
        int d = ei[N_EDGES + t];
        int s = ei[t];
        int b = batch[d];
        int pos = atomicAdd(&cursor[d], 1) + partials[d >> 8];
        quad[pos] = (unsigned long long)(unsigned)s
                  | ((unsigned long long)(unsigned)d << 17)
                  | ((unsigned long long)(unsigned)t << 34)
                  | ((unsigned long long)(unsigned)b << 54);
        if (do_ea) {   // write this edge's bf16 attrs at its SORTED position
            const float4* ea4 = (const float4*)ea;
            uint4* dst16 = (uint4*)&eab[(size_t)pos * 32];
            #pragma unroll
            for (int j = 0; j < 4; ++j) {
                float4 v0 = ea4[(size_t)t * 8 + j * 2 + 0];
                float4 v1 = ea4[(size_t)t * 8 + j * 2 + 1];
                uint4 pk;
                pk.x = pack_bf2(v0.x, v0.y); pk.y = pack_bf2(v0.z, v0.w);
                pk.z = pack_bf2(v1.x, v1.y); pk.w = pack_bf2(v1.z, v1.w);
                dst16[j] = pk;
            }
        }
    }
}

// ---------------------------------------------------------------------------
// Edge kernel: one 64-edge dst-sorted tile per block. ZERO LDS, ZERO barriers.
// Lane owns A-row eh*32+col; loads 12 A-frags direct from global. After the
// MFMAs, the dst-run reduction runs entirely in-register: the lane that
// reduces channel ch already computed C[.][ch] — only the `half` dimension
// must be exchanged, done with 8 shfl_xor(32). dst ids come via shfl from
// the quad registers. Atomics are wave-coalesced per run.
// ---------------------------------------------------------------------------
template<bool EAB>
__global__ __launch_bounds__(256, 8) void edge_kernel(
    const unsigned short* __restrict__ xb, const float* __restrict__ ea,
    const unsigned short* __restrict__ eab, const unsigned short* __restrict__ ub,
    const unsigned short* __restrict__ W1t, const float* __restrict__ b1,
    const unsigned long long* __restrict__ quad, float* __restrict__ agg)
{
    const int tid  = threadIdx.x;
    const int lane = tid & 63;
    const int wv   = tid >> 6;
    const int tile = blockIdx.x;
    const int eh   = wv >> 1;            // edge half: rows [eh*32, eh*32+32)
    const int nh   = wv & 1;             // channel half
    const int col  = lane & 31;
    const int half = lane >> 5;

    // Per-lane indices for A-row (eh*32 + col); both halves load same addr.
    const int sidx = tile * 64 + eh * 32 + col;   // sorted edge index
    unsigned long long p = quad[sidx];
    const int e_src = (int)(p & 0x1FFFF);
    const int e_dst = (int)((p >> 17) & 0x1FFFF);
    const int e_eid = (int)((p >> 34) & 0xFFFFF);
    const int e_b   = (int)(p >> 54);

    const int ch = nh * 32 + col;        // this lane's output channel
    const float b1v = b1[ch];

    floatx16 acc = {0,0,0,0,0,0,0,0,0,0,0,0,0,0,0,0};
    #pragma unroll
    for (int s = 0; s < 12; ++s) {
        bf16x8 a;
        if (s < 4) {
            a = __builtin_bit_cast(bf16x8,
                *(const ushort8_t*)&xb[e_dst * 64 + s * 16 + half * 8]);
        } else if (s < 8) {
            a = __builtin_bit_cast(bf16x8,
                *(const ushort8_t*)&xb[e_src * 64 + (s - 4) * 16 + half * 8]);
        } else if (s < 10) {
            if (EAB) {   // sorted bf16 attrs -> coalesced load
                a = __builtin_bit_cast(bf16x8,
                    *(const ushort8_t*)&eab[(size_t)sidx * 32 + (s - 8) * 16 + half * 8]);
            } else {
                const float4* ea4 = (const float4*)ea;
                float4 v0 = ea4[(size_t)e_eid * 8 + (s - 8) * 4 + half * 2 + 0];
                float4 v1 = ea4[(size_t)e_eid * 8 + (s - 8) * 4 + half * 2 + 1];
                uint4 uu;
                uu.x = pack_bf2(v0.x, v0.y); uu.y = pack_bf2(v0.z, v0.w);
                uu.z = pack_bf2(v1.x, v1.y); uu.w = pack_bf2(v1.z, v1.w);
                a = __builtin_bit_cast(bf16x8, uu);
            }
        } else {
            a = __builtin_bit_cast(bf16x8,
                *(const ushort8_t*)&ub[e_b * 32 + (s - 10) * 16 + half * 8]);
        }
        bf16x8 b = __builtin_bit_cast(bf16x8,
            *(const ushort8_t*)&W1t[ch * K1 + s * 16 + half * 8]);
        acc = __builtin_amdgcn_mfma_f32_32x32x16_bf16(a, b, acc, 0, 0, 0);
    }

    // bias + relu in C layout: own[r] = msg[row=(r&3)+8*(r>>2)+4*half][ch]
    float own[16];
    #pragma unroll
    for (int r = 0; r < 16; ++r) {
        float vv = acc[r] + b1v;
        own[r] = vv > 0.f ? vv : 0.f;
    }

    // Exchange across the half bit: h0 lane needs partner r0..7, h1 needs r8..15
    float rec[8];
    #pragma unroll
    for (int j = 0; j < 8; ++j) {
        float send = half ? own[j] : own[j + 8];
        rec[j] = __shfl_xor(send, 32, 64);
    }

    // Segmented dst-run reduction: lane reduces channel ch over 16 consecutive
    // edges [eh*32 + half*16, +16). Value for local edge i:
    //   h=0: i<4:own[i]  i<8:rec[i-4]  i<12:own[i-4]  else:rec[i-8]
    //   h=1: i<4:rec[i]  i<8:own[i+4]  i<12:rec[i-4]  else:own[i]
    int cur = __shfl(e_dst, half * 16, 64);
    float run = 0.f;
    #pragma unroll
    for (int i = 0; i < 16; ++i) {
        int d = __shfl(e_dst, half * 16 + i, 64);
        float v;
        if (i < 4)       v = half ? rec[i]     : own[i];
        else if (i < 8)  v = half ? own[i + 4] : rec[i - 4];
        else if (i < 12) v = half ? rec[i - 4] : own[i - 4];
        else             v = half ? own[i]     : rec[i - 8];
        if (d != cur) {
            atomicAdd(&agg[(size_t)cur * 64 + ch], run);
            run = 0.f;
            cur = d;
        }
        run += v;
    }
    atomicAdd(&agg[(size_t)cur * 64 + ch], run);
}

// ---------------------------------------------------------------------------
// Node kernel: out = relu([x, agg, u[batch]] @ W2 + b2). Direct per-lane
// A-frag loads (agg fp32 -> bf16 packed in-register), ONE barrier to order
// in-place agg reads (d_out) before out writes, no LDS staging.
// ---------------------------------------------------------------------------
__global__ __launch_bounds__(256, 4) void node_kernel(
    const unsigned short* __restrict__ xb, const unsigned short* __restrict__ ub,
    const int* __restrict__ batch, const unsigned short* __restrict__ W2t,
    const float* __restrict__ b2, float* __restrict__ out)
{
    const int tid  = threadIdx.x;
    const int lane = tid & 63;
    const int wv   = tid >> 6;
    const int base = blockIdx.x * 64;
    const int eh   = wv >> 1;
    const int nh   = wv & 1;
    const int col  = lane & 31;
    const int half = lane >> 5;

    const int n_a = base + eh * 32 + col;
    const int ns  = (n_a < N_NODES) ? n_a : (N_NODES - 1);  // clamp stays in-tile
    const int bn  = batch[ns];
    const int ch  = nh * 32 + col;

    bf16x8 Af[10];
    #pragma unroll
    for (int s = 0; s < 4; ++s)                              // x
        Af[s] = __builtin_bit_cast(bf16x8,
            *(const ushort8_t*)&xb[ns * 64 + s * 16 + half * 8]);
    #pragma unroll
    for (int s = 0; s < 4; ++s) {                            // agg (fp32 in d_out)
        float4 v0 = *(const float4*)&out[ns * 64 + s * 16 + half * 8 + 0];
        float4 v1 = *(const float4*)&out[ns * 64 + s * 16 + half * 8 + 4];
        uint4 pk;
        pk.x = pack_bf2(v0.x, v0.y); pk.y = pack_bf2(v0.z, v0.w);
        pk.z = pack_bf2(v1.x, v1.y); pk.w = pack_bf2(v1.z, v1.w);
        Af[4 + s] = __builtin_bit_cast(bf16x8, pk);
    }
    #pragma unroll
    for (int s = 0; s < 2; ++s)                              // u[batch]
        Af[8 + s] = __builtin_bit_cast(bf16x8,
            *(const ushort8_t*)&ub[bn * 32 + s * 16 + half * 8]);

    bf16x8 Bf[10];
    #pragma unroll
    for (int s = 0; s < 10; ++s)
        Bf[s] = __builtin_bit_cast(bf16x8,
            *(const ushort8_t*)&W2t[ch * K2 + s * 16 + half * 8]);
    const float b2v = b2[ch];

    __syncthreads();   // drain agg reads before any out writes (in-place)

    floatx16 acc = {0,0,0,0,0,0,0,0,0,0,0,0,0,0,0,0};
    #pragma unroll
    for (int s = 0; s < 10; ++s)
        acc = __builtin_amdgcn_mfma_f32_32x32x16_bf16(Af[s], Bf[s], acc, 0, 0, 0);

    #pragma unroll
    for (int r = 0; r < 16; ++r) {
        int n2 = base + eh * 32 + (r & 3) + 8 * (r >> 2) + 4 * half;
        if (n2 < N_NODES) {
            float vv = acc[r] + b2v;
            out[n2 * 64 + ch] = vv > 0.f ? vv : 0.f;
        }
    }
}

extern "C" void kernel_launch(void* const* d_in, const int* in_sizes, int n_in,
                              void* d_out, int out_size, void* d_ws, size_t ws_size,
                              hipStream_t stream) {
    const float* x     = (const float*)d_in[0];
    const int*   ei    = (const int*)d_in[1];
    const float* ea    = (const float*)d_in[2];
    const float* u     = (const float*)d_in[3];
    const int*   batch = (const int*)d_in[4];
    const float* W1    = (const float*)d_in[5];
    const float* b1    = (const float*)d_in[6];
    const float* W2    = (const float*)d_in[7];
    const float* b2    = (const float*)d_in[8];
    float* out = (float*)d_out;

    unsigned short* w1t  = (unsigned short*)((char*)d_ws + WS_W1T);
    unsigned short* w2t  = (unsigned short*)((char*)d_ws + WS_W2T);
    unsigned short* ub   = (unsigned short*)((char*)d_ws + WS_UB);
    int*            cur  = (int*)((char*)d_ws + WS_CUR);
    int*            part = (int*)((char*)d_ws + WS_PART);
    unsigned long long* quad = (unsigned long long*)((char*)d_ws + WS_QUAD);
    unsigned short* xb   = (unsigned short*)((char*)d_ws + WS_XB);
    unsigned short* eab  = (unsigned short*)((char*)d_ws + WS_EAB);

    const bool big = ws_size >= WS_EAB_END;   // room for sorted bf16 edge_attr?

    // agg accumulates in d_out; zero it + histogram/partials region
    hipMemsetAsync(out, 0, (size_t)out_size * sizeof(float), stream);
    hipMemsetAsync(cur, 0, WS_QUAD - WS_CUR, stream);

    prep_kernel<<<1024, 256, 0, stream>>>(x, u, W1, W2, ei, w1t, w2t, ub, xb, cur);
    scan1_kernel<<<NB_SCAN, 256, 0, stream>>>(cur, part);
    scan2_kernel<<<1, 512, 0, stream>>>(part);
    scatter_kernel<<<(N_EDGES + 255) / 256, 256, 0, stream>>>(
        ei, batch, ea, cur, part, quad, eab, big ? 1 : 0);
    if (big)
        edge_kernel<true><<<N_EDGES / 64, 256, 0, stream>>>(xb, ea, eab, ub, w1t, b1, quad, out);
    else
        edge_kernel<false><<<N_EDGES / 64, 256, 0, stream>>>(xb, ea, eab, ub, w1t, b1, quad, out);
    node_kernel<<<(N_NODES + 63) / 64, 256, 0, stream>>>(xb, ub, batch, w2t, b2, out);
}